// Round 25
// baseline (118.654 us; speedup 1.0000x reference)
//
#include <hip/hip_runtime.h>

// Polyphase 2x upsample, depthwise 12-tap, reflect pad, fp32.
// out[b,c,oh,ow] = 4 * sum_{m,n=0..5} x[b,c,reflect(q_y+py+m-3),reflect(q_x+px+n-3)]
//                       * filt[11-py-2m][11-px-2n],  oh=2*q_y+py, ow=2*q_x+px
//
// R22->R23: R22's 4-tile pipeline regressed (barriers+fewer blocks killed TLP)
// -> revert to R21 (79.8us best). ONE change: launch_bounds (256,4)->(256,6).
// Theory: all pipes individually < measured time; the loss is phase-overlap.
// 4 blocks/CU (50% occupancy) under-hides each block's load-wait->compute->
// store convoy. 6 blocks/CU = 75% occupancy; VGPR cap 85 > ~60 live, no spill.

#define S 40              // slab row stride in words
#define TW 1552           // per-tile buffer: 38x40 = 1520 used, pad tail

typedef float v2f __attribute__((ext_vector_type(2)));
typedef float v4f __attribute__((ext_vector_type(4)));
typedef __attribute__((address_space(3))) void lds_t;
typedef __attribute__((address_space(1))) const void gm_t;

__global__ void filter_prep(const float* __restrict__ filt, float* __restrict__ ws)
{
    int t = threadIdx.x;                 // scalar tap index 0..143
    if (t < 144) {
        int n = t % 6, m = (t / 6) % 6, px = (t / 36) & 1, py = t / 72;
        float f = 4.0f * filt[(11 - py - 2 * m) * 12 + (11 - px - 2 * n)];
        ws[2 * t]     = f;               // duplicated (f,f) pair for v_pk_fma
        ws[2 * t + 1] = f;
    }
}

__global__ __launch_bounds__(256, 6) void upsample2d_kernel(
    const float* __restrict__ x, const v2f* __restrict__ ftp,
    float* __restrict__ out)
{
    __shared__ float s_in[2 * TW];        // 12416 B: two block-shared tile slabs

    const int tx = threadIdx.x, ty = threadIdx.y;
    const int w    = ty >> 2;             // wave id 0..3
    const int lane = (ty & 3) * 16 + tx;  // HW lane id within wave
    const int bc0 = blockIdx.z;           // batch b=bc0>>6 (0..1), chan=bc0&63
    const int boy = blockIdx.y, box = blockIdx.x;

    // ---- block-shared slab: rows 0..37 = x rows boy*32-3 .. +34, cols -3..+36 ----
    int goff[6];
    #pragma unroll
    for (int k = 0; k < 6; ++k) {
        int j = w * 384 + 64 * k + lane;  // slab word 0..1535
        if (j > 1519) j = 1519;           // tail: dest lands in pad
        int r = (j * 1639) >> 16;         // j / 40
        int c = j - r * 40;
        int gy = boy * 32 - 3 + r, gx = box * 32 - 3 + c;
        gy = gy < 0 ? -gy : gy;  gy = gy > 255 ? 510 - gy : gy;
        gx = gx < 0 ? -gx : gx;  gx = gx > 255 ? 510 - gx : gx;
        goff[k] = gy * 256 + gx;
    }

    const float* x0 = x + (size_t)bc0 * 65536;            // batch b
    const float* x1 = x0 + (size_t)128 * 65536;           // batch b+2

    // ---- issue ALL staging up front: 6 chunks tile0, 6 chunks tile1 ----
    #pragma unroll
    for (int k = 0; k < 6; ++k)
        __builtin_amdgcn_global_load_lds((gm_t*)(x0 + goff[k]),
                                         (lds_t*)(s_in + w * 384 + 64 * k), 4, 0, 0);
    #pragma unroll
    for (int k = 0; k < 6; ++k)
        __builtin_amdgcn_global_load_lds((gm_t*)(x1 + goff[k]),
                                         (lds_t*)(s_in + TW + w * 384 + 64 * k), 4, 0, 0);

    const int xb  = (2 * ty) * S + 2 * tx;   // thread window: slab rows 2ty..2ty+7
    const int OY0 = boy * 64 + 4 * ty;
    const int OX  = box * 64 + 4 * tx;

    // ---- per-tile compute+store: proven core, nt stores ----
    auto tile = [&](const int sbase, float* oc) {
        v2f accp[4][2] = {};              // (out[oy][px], out[oy][2+px])
        #pragma unroll
        for (int r = 0; r < 8; ++r) {
            const int rb = sbase + xb + r * S;
            v2f e[4], o[3];
            #pragma unroll
            for (int j = 0; j < 4; ++j)   // even pairs: cols (2j, 2j+1)
                e[j] = *reinterpret_cast<const v2f*>(&s_in[rb + 2 * j]);
            #pragma unroll
            for (int j = 0; j < 3; ++j) { // odd pairs from LDS (proven form)
                o[j].x = s_in[rb + 2 * j + 1];
                o[j].y = s_in[rb + 2 * j + 2];
            }
            #pragma unroll
            for (int qy = 0; qy < 2; ++qy)
            #pragma unroll
            for (int py = 0; py < 2; ++py) {
                const int m = r - qy - py;
                if (m >= 0 && m <= 5) {
                    #pragma unroll
                    for (int px = 0; px < 2; ++px)
                    #pragma unroll
                    for (int n = 0; n < 6; ++n) {
                        const int c = px + n;
                        const v2f xp = (c & 1) ? o[(c - 1) >> 1] : e[c >> 1];
                        const v2f f2 = ftp[((py * 2 + px) * 6 + m) * 6 + n];
                        accp[2 * qy + py][px] =
                            __builtin_elementwise_fma(xp, f2, accp[2 * qy + py][px]);
                    }
                }
            }
        }
        #pragma unroll
        for (int oy = 0; oy < 4; ++oy) {
            v4f v = (v4f){accp[oy][0].x, accp[oy][1].x,
                          accp[oy][0].y, accp[oy][1].y};
            __builtin_nontemporal_store(v,
                reinterpret_cast<v4f*>(&oc[(size_t)(OY0 + oy) * 512 + OX]));
        }
    };

    // tile 0: own 6 loads done -> barrier => ALL waves' tile0 chunks landed.
    asm volatile("s_waitcnt vmcnt(6)" ::: "memory");
    __builtin_amdgcn_sched_barrier(0);
    __builtin_amdgcn_s_barrier();
    __builtin_amdgcn_sched_barrier(0);
    tile(0, out + (size_t)bc0 * 262144);

    // tile 1: outstanding = 6 tile1-loads (oldest) + 16 tile0-stores.
    // vmcnt(16): in-order retire => the 6 loads completed; stores not drained.
    asm volatile("s_waitcnt vmcnt(16)" ::: "memory");
    __builtin_amdgcn_sched_barrier(0);
    __builtin_amdgcn_s_barrier();
    __builtin_amdgcn_sched_barrier(0);
    tile(TW, out + (size_t)(bc0 + 128) * 262144);
}

extern "C" void kernel_launch(void* const* d_in, const int* in_sizes, int n_in,
                              void* d_out, int out_size, void* d_ws, size_t ws_size,
                              hipStream_t stream) {
    const float* x    = (const float*)d_in[0];   // (4,64,256,256) fp32
    const float* filt = (const float*)d_in[1];   // (12,12) fp32
    float* out = (float*)d_out;                  // (4,64,512,512) fp32
    float* ws  = (float*)d_ws;                   // 1152 B duplicated filter table

    filter_prep<<<dim3(1), dim3(256), 0, stream>>>(filt, ws);

    dim3 grid(8, 8, 128);   // 8x8 tiles; z = (batch 0..1, channel); +batch+2 in-kernel
    dim3 block(16, 16, 1);
    upsample2d_kernel<<<grid, block, 0, stream>>>(x, (const v2f*)ws, out);
}

// Round 26
// 75.954 us; speedup vs baseline: 1.5622x; 1.5622x over previous
//
#include <hip/hip_runtime.h>

// Polyphase 2x upsample, depthwise 12-tap, reflect pad, fp32.
// out[b,c,oh,ow] = 4 * sum_{m,n=0..5} x[b,c,reflect(q_y+py+m-3),reflect(q_x+px+n-3)]
//                       * filt[11-py-2m][11-px-2n],  oh=2*q_y+py, ow=2*q_x+px
//
// R25->R26: (256,6) regressed (118us, spill — 2nd confirmation after R11) ->
// revert to R21 exact (79.8us best, (256,4)). ONE change: XCD-aware spatial
// swizzle. Halo re-fetch (~26MB) reaches HBM because x-neighbor tiles land on
// different XCDs (round-robin dispatch). Bijective remap: 64 tiles -> 8
// regions of 4x2; region id R = bid&7 = (dispatch id mod 8) = XCD, so each
// XCD gets a contiguous region and internal halos hit its L2.
// Predict FETCH 90->~72MB, dur 79.8->76-78.

#define S 40              // slab row stride in words
#define TW 1552           // per-tile buffer: 38x40 = 1520 used, pad tail

typedef float v2f __attribute__((ext_vector_type(2)));
typedef float v4f __attribute__((ext_vector_type(4)));
typedef __attribute__((address_space(3))) void lds_t;
typedef __attribute__((address_space(1))) const void gm_t;

__global__ void filter_prep(const float* __restrict__ filt, float* __restrict__ ws)
{
    int t = threadIdx.x;                 // scalar tap index 0..143
    if (t < 144) {
        int n = t % 6, m = (t / 6) % 6, px = (t / 36) & 1, py = t / 72;
        float f = 4.0f * filt[(11 - py - 2 * m) * 12 + (11 - px - 2 * n)];
        ws[2 * t]     = f;               // duplicated (f,f) pair for v_pk_fma
        ws[2 * t + 1] = f;
    }
}

__global__ __launch_bounds__(256, 4) void upsample2d_kernel(
    const float* __restrict__ x, const v2f* __restrict__ ftp,
    float* __restrict__ out)
{
    __shared__ float s_in[2 * TW];        // 12416 B: two block-shared tile slabs

    const int tx = threadIdx.x, ty = threadIdx.y;
    const int w    = ty >> 2;             // wave id 0..3
    const int lane = (ty & 3) * 16 + tx;  // HW lane id within wave
    const int bc0 = blockIdx.z;           // batch b=bc0>>6 (0..1), chan=bc0&63

    // ---- XCD-aware spatial swizzle (bijective): 8 regions of 4x2 tiles ----
    // dispatch id mod 8 == bid mod 8 == R -> all 8 tiles of region R on XCD R.
    const int bid = blockIdx.x + 8 * blockIdx.y;   // 0..63
    const int R   = bid & 7, r = bid >> 3;
    const int box = (R & 1) * 4 + (r & 3);         // tile col 0..7
    const int boy = (R >> 1) * 2 + (r >> 2);       // tile row 0..7

    // ---- block-shared slab: rows 0..37 = x rows boy*32-3 .. +34, cols -3..+36 ----
    int goff[6];
    #pragma unroll
    for (int k = 0; k < 6; ++k) {
        int j = w * 384 + 64 * k + lane;  // slab word 0..1535
        if (j > 1519) j = 1519;           // tail: dest lands in pad
        int r2 = (j * 1639) >> 16;        // j / 40
        int c = j - r2 * 40;
        int gy = boy * 32 - 3 + r2, gx = box * 32 - 3 + c;
        gy = gy < 0 ? -gy : gy;  gy = gy > 255 ? 510 - gy : gy;
        gx = gx < 0 ? -gx : gx;  gx = gx > 255 ? 510 - gx : gx;
        goff[k] = gy * 256 + gx;
    }

    const float* x0 = x + (size_t)bc0 * 65536;            // batch b
    const float* x1 = x0 + (size_t)128 * 65536;           // batch b+2

    // ---- issue ALL staging up front: 6 chunks tile0, 6 chunks tile1 ----
    #pragma unroll
    for (int k = 0; k < 6; ++k)
        __builtin_amdgcn_global_load_lds((gm_t*)(x0 + goff[k]),
                                         (lds_t*)(s_in + w * 384 + 64 * k), 4, 0, 0);
    #pragma unroll
    for (int k = 0; k < 6; ++k)
        __builtin_amdgcn_global_load_lds((gm_t*)(x1 + goff[k]),
                                         (lds_t*)(s_in + TW + w * 384 + 64 * k), 4, 0, 0);

    const int xb  = (2 * ty) * S + 2 * tx;   // thread window: slab rows 2ty..2ty+7
    const int OY0 = boy * 64 + 4 * ty;
    const int OX  = box * 64 + 4 * tx;

    // ---- per-tile compute+store: proven core, nt stores ----
    auto tile = [&](const int sbase, float* oc) {
        v2f accp[4][2] = {};              // (out[oy][px], out[oy][2+px])
        #pragma unroll
        for (int r8 = 0; r8 < 8; ++r8) {
            const int rb = sbase + xb + r8 * S;
            v2f e[4], o[3];
            #pragma unroll
            for (int j = 0; j < 4; ++j)   // even pairs: cols (2j, 2j+1)
                e[j] = *reinterpret_cast<const v2f*>(&s_in[rb + 2 * j]);
            #pragma unroll
            for (int j = 0; j < 3; ++j) { // odd pairs from LDS (proven form)
                o[j].x = s_in[rb + 2 * j + 1];
                o[j].y = s_in[rb + 2 * j + 2];
            }
            #pragma unroll
            for (int qy = 0; qy < 2; ++qy)
            #pragma unroll
            for (int py = 0; py < 2; ++py) {
                const int m = r8 - qy - py;
                if (m >= 0 && m <= 5) {
                    #pragma unroll
                    for (int px = 0; px < 2; ++px)
                    #pragma unroll
                    for (int n = 0; n < 6; ++n) {
                        const int c = px + n;
                        const v2f xp = (c & 1) ? o[(c - 1) >> 1] : e[c >> 1];
                        const v2f f2 = ftp[((py * 2 + px) * 6 + m) * 6 + n];
                        accp[2 * qy + py][px] =
                            __builtin_elementwise_fma(xp, f2, accp[2 * qy + py][px]);
                    }
                }
            }
        }
        #pragma unroll
        for (int oy = 0; oy < 4; ++oy) {
            v4f v = (v4f){accp[oy][0].x, accp[oy][1].x,
                          accp[oy][0].y, accp[oy][1].y};
            __builtin_nontemporal_store(v,
                reinterpret_cast<v4f*>(&oc[(size_t)(OY0 + oy) * 512 + OX]));
        }
    };

    // tile 0: own 6 loads done -> barrier => ALL waves' tile0 chunks landed.
    asm volatile("s_waitcnt vmcnt(6)" ::: "memory");
    __builtin_amdgcn_sched_barrier(0);
    __builtin_amdgcn_s_barrier();
    __builtin_amdgcn_sched_barrier(0);
    tile(0, out + (size_t)bc0 * 262144);

    // tile 1: outstanding = 6 tile1-loads (oldest) + 16 tile0-stores.
    // vmcnt(16): in-order retire => the 6 loads completed; stores not drained.
    asm volatile("s_waitcnt vmcnt(16)" ::: "memory");
    __builtin_amdgcn_sched_barrier(0);
    __builtin_amdgcn_s_barrier();
    __builtin_amdgcn_sched_barrier(0);
    tile(TW, out + (size_t)(bc0 + 128) * 262144);
}

extern "C" void kernel_launch(void* const* d_in, const int* in_sizes, int n_in,
                              void* d_out, int out_size, void* d_ws, size_t ws_size,
                              hipStream_t stream) {
    const float* x    = (const float*)d_in[0];   // (4,64,256,256) fp32
    const float* filt = (const float*)d_in[1];   // (12,12) fp32
    float* out = (float*)d_out;                  // (4,64,512,512) fp32
    float* ws  = (float*)d_ws;                   // 1152 B duplicated filter table

    filter_prep<<<dim3(1), dim3(256), 0, stream>>>(filt, ws);

    dim3 grid(8, 8, 128);   // 8x8 tiles; z = (batch 0..1, channel); +batch+2 in-kernel
    dim3 block(16, 16, 1);
    upsample2d_kernel<<<grid, block, 0, stream>>>(x, (const v2f*)ws, out);
}